// Round 2
// 235.332 us; speedup vs baseline: 1.0047x; 1.0047x over previous
//
#include <hip/hip_runtime.h>

#define N_NODES 50000
#define N_EDGES 800000
#define IN_FEATS 256
#define HIDDEN 128
#define OUT_FEATS 64

// ---- LDS-histogram decomposition (packed u16 counters) ----
// R12: NB 16384->8192 (32 KB LDS -> 4-5 blocks/CU vs 1-2; hist/fill were
// latency-bound at 1 wave/SIMD), NRANGE 4->7. gemm1 fused into hist launch
// (independent work: ns scaling moved into gather1 by linearity).
// R13: resubmit — R12 bench died on container acquisition (infra), no
// counter evidence against the candidate; audit found no OOB/hang path.
#define NB 8192              // bins per range (2 bins/u32 word -> 16 KB LDS)
#define NRANGE 7             // ceil(50000/8192)
#define NBT (NRANGE * NB)    // 57344 padded bins per copy (u16 each)
#define NCHUNK 64            // edge chunks (= privatized copies)
#define EPC 12500            // edges per chunk; per-bin count <= 12500 < 2^16
#define HBLK (NRANGE * NCHUNK)           // 448 hist blocks
#define ROWBLK ((N_NODES + 63) / 64)     // 782
#define G1BLK (ROWBLK * 2)               // 1564 gemm1 blocks (COLBLK=2)

typedef _Float16 f16;
typedef _Float16 f16x2 __attribute__((ext_vector_type(2)));
typedef _Float16 f16x8 __attribute__((ext_vector_type(8)));
typedef float f32x4 __attribute__((ext_vector_type(4)));

// ------------------------------------------- fused hist + gemm1 kernel
// Blocks [0,448): LDS histogram of src/dst (zero global atomics) + W2T
// transpose fold on blocks 0-31. Blocks [448, 2012): gemm1 m1 = f16(X)@W1
// (UNSCALED — norm_src applied per-edge in gather1; f16 is floating so
// scale-after-round == scale-before-round in relative error). gemm1 blocks
// co-resident with hist blocks give the hist waves latency-hiding partners
// and hide gemm1's duration under the CSR-build phase.
__global__ __launch_bounds__(256) void hist_gemm_kernel(
    const int* __restrict__ src, const int* __restrict__ dst,
    unsigned* __restrict__ hist_src, unsigned* __restrict__ hist_dst,
    const float* __restrict__ W1, const float* __restrict__ W2,
    f16* __restrict__ W2T, const float* __restrict__ x,
    f16* __restrict__ m1) {
  // union: hist counters (32 KB) / gemm B-tile 64x(256+8) f16 (33.8 KB)
  __shared__ __align__(16) unsigned smem[8448];  // 33792 B
  if (blockIdx.x < HBLK) {
    unsigned* ls = smem;            // [NB/2] packed u16 src-degree bins
    unsigned* ld2 = smem + NB / 2;  // [NB/2] packed u16 dst-degree bins
    const int r = blockIdx.x % NRANGE;
    const int c = blockIdx.x / NRANGE;
    const int lo = r * NB;
    for (int i = threadIdx.x; i < NB / 2; i += 256) {
      ls[i] = 0;
      ld2[i] = 0;
    }
    __syncthreads();
    const int4* s4 = (const int4*)(src + c * EPC);
    const int4* d4 = (const int4*)(dst + c * EPC);
    for (int i = threadIdx.x; i < EPC / 4; i += 256) {
      int4 s = s4[i];
      int4 d = d4[i];
      unsigned b;
      b = (unsigned)(s.x - lo); if (b < NB) atomicAdd(&ls[b >> 1], 1u << ((b & 1) << 4));
      b = (unsigned)(s.y - lo); if (b < NB) atomicAdd(&ls[b >> 1], 1u << ((b & 1) << 4));
      b = (unsigned)(s.z - lo); if (b < NB) atomicAdd(&ls[b >> 1], 1u << ((b & 1) << 4));
      b = (unsigned)(s.w - lo); if (b < NB) atomicAdd(&ls[b >> 1], 1u << ((b & 1) << 4));
      b = (unsigned)(d.x - lo); if (b < NB) atomicAdd(&ld2[b >> 1], 1u << ((b & 1) << 4));
      b = (unsigned)(d.y - lo); if (b < NB) atomicAdd(&ld2[b >> 1], 1u << ((b & 1) << 4));
      b = (unsigned)(d.z - lo); if (b < NB) atomicAdd(&ld2[b >> 1], 1u << ((b & 1) << 4));
      b = (unsigned)(d.w - lo); if (b < NB) atomicAdd(&ld2[b >> 1], 1u << ((b & 1) << 4));
    }
    __syncthreads();
    unsigned* hs = hist_src + ((long)c * NBT + lo) / 2;
    unsigned* hd = hist_dst + ((long)c * NBT + lo) / 2;
    for (int i = threadIdx.x; i < NB / 2; i += 256) {
      hs[i] = ls[i];
      hd[i] = ld2[i];
    }
    // folded W2 transpose: 8192 elems on blocks 0-31
    if (blockIdx.x < 32) {
      int j = blockIdx.x * 256 + threadIdx.x;
      int n = j >> 7, k = j & 127;
      W2T[j] = (f16)W2[k * 64 + n];
    }
  } else {
    // ---------------- gemm1: 64x64 tile, on-the-fly W1 transpose into LDS
    f16* Bs = (f16*)smem;
    constexpr int KP = IN_FEATS + 8;  // padded LDS row stride (f16)
    const int bid = blockIdx.x - HBLK;
    const int cb = bid & 1;           // COLBLK = 2
    const int rb = bid >> 1;
    const int col0 = cb * 64;
    const int wave = threadIdx.x >> 6;
    const int lane = threadIdx.x & 63;
    const int m = lane & 15;
    const int q = lane >> 4;
    const int row0 = rb * 64 + wave * 16;

    // Bs[n][k] = W1[k][col0+n]; W1 is 128 KB, L2-resident (re-read per
    // block is cheap). Pair-packed f16x2 writes halve LDS-conflict cost.
    for (int idx = threadIdx.x; idx < 64 * (IN_FEATS / 2); idx += 256) {
      int k2 = idx >> 6;   // 0..127 -> k = 2*k2
      int n = idx & 63;    // coalesced over lanes
      float a0 = W1[(2 * k2) * HIDDEN + col0 + n];
      float a1 = W1[(2 * k2 + 1) * HIDDEN + col0 + n];
      f16x2 pk;
      pk[0] = (f16)a0;
      pk[1] = (f16)a1;
      *(f16x2*)(Bs + n * KP + 2 * k2) = pk;
    }
    __syncthreads();

    const int ra = min(row0 + m, N_NODES - 1);
    f32x4 acc[4];
#pragma unroll
    for (int t = 0; t < 4; ++t) acc[t] = (f32x4){0.f, 0.f, 0.f, 0.f};

#pragma unroll
    for (int ki = 0; ki < IN_FEATS / 32; ++ki) {
      const int kb = ki * 32 + q * 8;
      const float* p = x + (long)ra * IN_FEATS + kb;
      float4 u0 = *(const float4*)p;
      float4 u1 = *(const float4*)(p + 4);
      f16x8 a;
      a[0] = (f16)u0.x; a[1] = (f16)u0.y;
      a[2] = (f16)u0.z; a[3] = (f16)u0.w;
      a[4] = (f16)u1.x; a[5] = (f16)u1.y;
      a[6] = (f16)u1.z; a[7] = (f16)u1.w;
#pragma unroll
      for (int t = 0; t < 4; ++t) {
        f16x8 bfr = *(const f16x8*)(Bs + (t * 16 + m) * KP + kb);
        acc[t] = __builtin_amdgcn_mfma_f32_16x16x32_f16(a, bfr, acc[t], 0, 0, 0);
      }
    }

#pragma unroll
    for (int rr = 0; rr < 4; ++rr) {
      int row = row0 + q * 4 + rr;
      if (row < N_NODES) {
#pragma unroll
        for (int t = 0; t < 4; ++t)
          m1[(long)row * HIDDEN + col0 + t * 16 + m] = (f16)acc[t][rr];
      }
    }
  }
}

// sum copies -> norms; hist_dst -> exclusive prefix over copies (u16; max
// in-degree ~50 << 2^16); emits per-block degree sums (folded scan1).
__global__ __launch_bounds__(256) void reduce_kernel(
    const unsigned* __restrict__ hist_src, unsigned* __restrict__ hist_dst,
    int* __restrict__ deg_in, float* __restrict__ norm_src,
    float* __restrict__ norm_dst, int* __restrict__ partial) {
  const unsigned short* hs = (const unsigned short*)hist_src;
  unsigned short* hd = (unsigned short*)hist_dst;
  int n = blockIdx.x * 256 + threadIdx.x;
  int run = 0;
  if (n < N_NODES) {
    int so = 0;
#pragma unroll 8
    for (int c = 0; c < NCHUNK; ++c) so += hs[(long)c * NBT + n];
    norm_src[n] = rsqrtf((float)max(so, 1));
#pragma unroll 8
    for (int c = 0; c < NCHUNK; ++c) {
      int t = hd[(long)c * NBT + n];
      hd[(long)c * NBT + n] = (unsigned short)run;
      run += t;
    }
    deg_in[n] = run;
    norm_dst[n] = rsqrtf((float)max(run, 1));
  }
  __shared__ int sd[256];
  sd[threadIdx.x] = run;
  __syncthreads();
  for (int s = 128; s > 0; s >>= 1) {
    if (threadIdx.x < s) sd[threadIdx.x] += sd[threadIdx.x + s];
    __syncthreads();
  }
  if (threadIdx.x == 0) partial[blockIdx.x] = sd[0];
}

// ------------------------------------------------- scan (scan2 folded in)
__global__ __launch_bounds__(256) void scan3(const int* __restrict__ deg,
                                             const int* __restrict__ partial,
                                             int* __restrict__ rowptr) {
  __shared__ int sd[256];
  __shared__ int sp[256];
  const int w = blockIdx.x;
  int pv = (threadIdx.x < 196) ? partial[threadIdx.x] : 0;
  sp[threadIdx.x] = pv;
  __syncthreads();
  for (int off = 1; off < 256; off <<= 1) {
    int t = sp[threadIdx.x] +
            ((threadIdx.x >= off) ? sp[threadIdx.x - off] : 0);
    __syncthreads();
    sp[threadIdx.x] = t;
    __syncthreads();
  }
  const int base = (w == 0) ? 0 : sp[w - 1];
  int i = w * 256 + threadIdx.x;
  int v = (i < N_NODES) ? deg[i] : 0;
  sd[threadIdx.x] = v;
  __syncthreads();
  for (int off = 1; off < 256; off <<= 1) {
    int t = sd[threadIdx.x] +
            ((threadIdx.x >= off) ? sd[threadIdx.x - off] : 0);
    __syncthreads();
    sd[threadIdx.x] = t;
    __syncthreads();
  }
  if (i < N_NODES) rowptr[i] = base + sd[threadIdx.x] - v;
  if (w == 0 && threadIdx.x == 0) rowptr[N_NODES] = N_EDGES;
}

// ------------------------------------------------------------- CSR fill
// R12: 32 KB cur[] (NB=8192) -> ~2x resident waves vs 64 KB version.
__global__ __launch_bounds__(256) void fill_csr(
    const int* __restrict__ src, const int* __restrict__ dst,
    const int* __restrict__ rowptr, const unsigned* __restrict__ pref32,
    int* __restrict__ col) {
  __shared__ int cur[NB];  // 32 KB
  const unsigned short* pref = (const unsigned short*)pref32;
  const int r = blockIdx.x % NRANGE;
  const int c = blockIdx.x / NRANGE;
  const int lo = r * NB;
  for (int i = threadIdx.x; i < NB; i += 256) {
    int n = lo + i;
    cur[i] = (n < N_NODES) ? rowptr[n] + pref[(long)c * NBT + n] : 0;
  }
  __syncthreads();
  const int4* s4 = (const int4*)(src + c * EPC);
  const int4* d4 = (const int4*)(dst + c * EPC);
  for (int i = threadIdx.x; i < EPC / 4; i += 256) {
    int4 s = s4[i];
    int4 d = d4[i];
    unsigned b;
    b = (unsigned)(d.x - lo);
    if (b < NB) col[atomicAdd(&cur[b], 1)] = s.x;
    b = (unsigned)(d.y - lo);
    if (b < NB) col[atomicAdd(&cur[b], 1)] = s.y;
    b = (unsigned)(d.z - lo);
    if (b < NB) col[atomicAdd(&cur[b], 1)] = s.z;
    b = (unsigned)(d.w - lo);
    if (b < NB) col[atomicAdd(&cur[b], 1)] = s.w;
  }
}

// ------------------------------------------------------------- MFMA GEMM
// (layer 2 only now; layer 1 is fused into hist_gemm_kernel)
template <int K, int NC, int TN, bool FP32IN>
__global__ __launch_bounds__(256) void gemm_mfma(
    const void* __restrict__ Xv, const f16* __restrict__ WT,
    const float* __restrict__ ns, f16* __restrict__ Mout) {
  constexpr int KI = K / 32;
  constexpr int COLBLK = NC / (TN * 16);
  constexpr int KP = K + 8;
  __shared__ f16 Bs[TN * 16 * KP];

  const int cb = blockIdx.x % COLBLK;
  const int rb = blockIdx.x / COLBLK;
  const int col0 = cb * TN * 16;
  const int wave = threadIdx.x >> 6;
  const int lane = threadIdx.x & 63;
  const int m = lane & 15;
  const int q = lane >> 4;
  const int row0 = rb * 64 + wave * 16;

  for (int idx = threadIdx.x; idx < TN * 16 * (K / 8); idx += 256) {
    int n = idx / (K / 8);
    int kk = idx % (K / 8);
    *(f16x8*)(Bs + n * KP + kk * 8) =
        *(const f16x8*)(WT + (long)(col0 + n) * K + kk * 8);
  }
  __syncthreads();

  const int ra = min(row0 + m, N_NODES - 1);
  const float s = FP32IN ? ns[ra] : 0.f;

  f32x4 acc[TN];
#pragma unroll
  for (int t = 0; t < TN; ++t) acc[t] = (f32x4){0.f, 0.f, 0.f, 0.f};

#pragma unroll
  for (int ki = 0; ki < KI; ++ki) {
    const int kb = ki * 32 + q * 8;
    f16x8 a;
    if (FP32IN) {
      const float* X = (const float*)Xv;
      const float* p = X + (long)ra * K + kb;
      float4 u0 = *(const float4*)p;
      float4 u1 = *(const float4*)(p + 4);
      a[0] = (f16)(u0.x * s); a[1] = (f16)(u0.y * s);
      a[2] = (f16)(u0.z * s); a[3] = (f16)(u0.w * s);
      a[4] = (f16)(u1.x * s); a[5] = (f16)(u1.y * s);
      a[6] = (f16)(u1.z * s); a[7] = (f16)(u1.w * s);
    } else {
      const f16* X = (const f16*)Xv;
      a = *(const f16x8*)(X + (long)ra * K + kb);
    }
#pragma unroll
    for (int t = 0; t < TN; ++t) {
      f16x8 b = *(const f16x8*)(Bs + (t * 16 + m) * KP + kb);
      acc[t] = __builtin_amdgcn_mfma_f32_16x16x32_f16(a, b, acc[t], 0, 0, 0);
    }
  }

#pragma unroll
  for (int r = 0; r < 4; ++r) {
    int row = row0 + q * 4 + r;
    if (row < N_NODES) {
#pragma unroll
      for (int t = 0; t < TN; ++t)
        Mout[(long)row * NC + col0 + t * 16 + m] = (f16)acc[t][r];
    }
  }
}

// ------------------------------------------------------------- gather-agg
// R6/R10 measured-best form; R12: per-edge ns[col] scaling (m1 now
// unscaled — scale-after-round has identical relative error in f16; the
// ns load is lane-uniform within each edge group -> broadcast, ~free).
__global__ __launch_bounds__(256) void gather1_kernel(
    const f16* __restrict__ M, const int* __restrict__ rowptr,
    const int* __restrict__ col, const float* __restrict__ nd,
    const float* __restrict__ ns, const float* __restrict__ b,
    f16* __restrict__ out) {
  constexpr int LPR = 16;       // 128 f16 = 256 B row / 16 B per lane
  constexpr int EPW = 64 / LPR; // 4 edges in parallel
  const int wave = threadIdx.x >> 6;
  const int lane = threadIdx.x & 63;
  const int eg = lane / LPR;
  const int t = lane % LPR;
  const int n = blockIdx.x * 4 + wave;
  if (n >= N_NODES) return;
  const int beg = rowptr[n];
  const int end = rowptr[n + 1];

  float acc[8];
#pragma unroll
  for (int j = 0; j < 8; ++j) acc[j] = 0.f;

  int i = beg + eg;
  for (; i + EPW < end; i += 2 * EPW) {
    int s0 = col[i];
    int s1 = col[i + EPW];
    float n0 = ns[s0];
    float n1 = ns[s1];
    f16x8 v0 = *(const f16x8*)(M + (long)s0 * HIDDEN + t * 8);
    f16x8 v1 = *(const f16x8*)(M + (long)s1 * HIDDEN + t * 8);
#pragma unroll
    for (int j = 0; j < 8; ++j)
      acc[j] += n0 * (float)v0[j] + n1 * (float)v1[j];
  }
  if (i < end) {
    int s0 = col[i];
    float n0 = ns[s0];
    f16x8 v0 = *(const f16x8*)(M + (long)s0 * HIDDEN + t * 8);
#pragma unroll
    for (int j = 0; j < 8; ++j) acc[j] += n0 * (float)v0[j];
  }

#pragma unroll
  for (int m2 = LPR; m2 < 64; m2 <<= 1)
#pragma unroll
    for (int j = 0; j < 8; ++j) acc[j] += __shfl_xor(acc[j], m2, 64);

  if (eg == 0) {
    float s = nd[n];
    float sn = ns[n];
    float4 bb0 = *(const float4*)(b + t * 8);
    float4 bb1 = *(const float4*)(b + t * 8 + 4);
    f16x8 o;
    o[0] = (f16)(fmaxf(acc[0] * s + bb0.x, 0.f) * sn);
    o[1] = (f16)(fmaxf(acc[1] * s + bb0.y, 0.f) * sn);
    o[2] = (f16)(fmaxf(acc[2] * s + bb0.z, 0.f) * sn);
    o[3] = (f16)(fmaxf(acc[3] * s + bb0.w, 0.f) * sn);
    o[4] = (f16)(fmaxf(acc[4] * s + bb1.x, 0.f) * sn);
    o[5] = (f16)(fmaxf(acc[5] * s + bb1.y, 0.f) * sn);
    o[6] = (f16)(fmaxf(acc[6] * s + bb1.z, 0.f) * sn);
    o[7] = (f16)(fmaxf(acc[7] * s + bb1.w, 0.f) * sn);
    *(f16x8*)(out + (long)n * HIDDEN + t * 8) = o;
  }
}

__global__ __launch_bounds__(256) void gather2_kernel(
    const f16* __restrict__ M, const int* __restrict__ rowptr,
    const int* __restrict__ col, const float* __restrict__ nd,
    const float* __restrict__ b, float* __restrict__ out) {
  constexpr int LPR = 8;        // 64 f16 = 128 B row / 16 B per lane
  constexpr int EPW = 64 / LPR; // 8 edges in parallel
  const int wave = threadIdx.x >> 6;
  const int lane = threadIdx.x & 63;
  const int eg = lane / LPR;
  const int t = lane % LPR;
  const int n = blockIdx.x * 4 + wave;
  if (n >= N_NODES) return;
  const int beg = rowptr[n];
  const int end = rowptr[n + 1];

  float acc[8];
#pragma unroll
  for (int j = 0; j < 8; ++j) acc[j] = 0.f;

  int i = beg + eg;
  for (; i + EPW < end; i += 2 * EPW) {
    int s0 = col[i];
    int s1 = col[i + EPW];
    f16x8 v0 = *(const f16x8*)(M + (long)s0 * OUT_FEATS + t * 8);
    f16x8 v1 = *(const f16x8*)(M + (long)s1 * OUT_FEATS + t * 8);
#pragma unroll
    for (int j = 0; j < 8; ++j) acc[j] += (float)v0[j] + (float)v1[j];
  }
  if (i < end) {
    int s0 = col[i];
    f16x8 v0 = *(const f16x8*)(M + (long)s0 * OUT_FEATS + t * 8);
#pragma unroll
    for (int j = 0; j < 8; ++j) acc[j] += (float)v0[j];
  }

#pragma unroll
  for (int m2 = LPR; m2 < 64; m2 <<= 1)
#pragma unroll
    for (int j = 0; j < 8; ++j) acc[j] += __shfl_xor(acc[j], m2, 64);

  if (eg == 0) {
    float s = nd[n];
    float4 bb0 = *(const float4*)(b + t * 8);
    float4 bb1 = *(const float4*)(b + t * 8 + 4);
    float4 o0, o1;
    o0.x = acc[0] * s + bb0.x;
    o0.y = acc[1] * s + bb0.y;
    o0.z = acc[2] * s + bb0.z;
    o0.w = acc[3] * s + bb0.w;
    o1.x = acc[4] * s + bb1.x;
    o1.y = acc[5] * s + bb1.y;
    o1.z = acc[6] * s + bb1.z;
    o1.w = acc[7] * s + bb1.w;
    *(float4*)(out + (long)n * OUT_FEATS + t * 8) = o0;
    *(float4*)(out + (long)n * OUT_FEATS + t * 8 + 4) = o1;
  }
}

extern "C" void kernel_launch(void* const* d_in, const int* in_sizes, int n_in,
                              void* d_out, int out_size, void* d_ws,
                              size_t ws_size, hipStream_t stream) {
  const float* x = (const float*)d_in[0];
  const int* src = (const int*)d_in[1];
  const int* dst = (const int*)d_in[2];
  const float* W1 = (const float*)d_in[3];
  const float* b1 = (const float*)d_in[4];
  const float* W2 = (const float*)d_in[5];
  const float* b2 = (const float*)d_in[6];
  float* out = (float*)d_out;

  // ---- workspace layout
  int* wi = (int*)d_ws;
  int* partial = wi;            // [256]
  int* rowptr = wi + 256;       // [50001] (pad to 50004)
  int* deg_in = wi + 50260;     // [50000]
  int* col = wi + 100260;       // [800000] -> ends at int 900260
  float* wf = (float*)d_ws + 900260;
  float* norm_src = wf;         // [50000]
  float* norm_dst = wf + 50000; // [50000]
  f16* fh = (f16*)(wf + 100000);
  f16* W2T = fh;                          // [64*128]
  f16* m1 = fh + 64 * 128;                // [50048*128]
  f16* h1p = m1 + (long)50048 * 128;      // [50048*128]
  f16* m2 = h1p + (long)50048 * 128;      // [50048*64]

  // hist overlay on h1p/m2 region (19.2 MB >= 14.7 MB): m1 must stay live
  // (gemm1 writes it during the hist launch now); h1p/m2 are dead until
  // gather1/gemm2, which run after fill_csr (stream-ordered).
  unsigned* hist_src = (unsigned*)h1p;                      // u16[NCHUNK*NBT]
  unsigned* hist_dst = hist_src + (long)NCHUNK * NBT / 2;   // u16[NCHUNK*NBT]

  const int nb_nodes = (N_NODES + 255) / 256;  // 196

  // ---- fused: degrees histogram + W2 transpose + gemm1 (independent work)
  hist_gemm_kernel<<<HBLK + G1BLK, 256, 0, stream>>>(
      src, dst, hist_src, hist_dst, W1, W2, W2T, x, m1);
  reduce_kernel<<<nb_nodes, 256, 0, stream>>>(hist_src, hist_dst, deg_in,
                                              norm_src, norm_dst, partial);
  scan3<<<nb_nodes, 256, 0, stream>>>(deg_in, partial, rowptr);
  fill_csr<<<HBLK, 256, 0, stream>>>(src, dst, rowptr, hist_dst, col);

  // ---- layer 1 aggregation (applies ns[src] per edge now)
  gather1_kernel<<<(N_NODES + 3) / 4, 256, 0, stream>>>(m1, rowptr, col,
                                                        norm_dst, norm_src, b1,
                                                        h1p);

  // ---- layer 2
  gemm_mfma<HIDDEN, OUT_FEATS, 4, false>
      <<<ROWBLK, 256, 0, stream>>>(h1p, W2T, norm_src, m2);
  gather2_kernel<<<(N_NODES + 3) / 4, 256, 0, stream>>>(m2, rowptr, col,
                                                        norm_dst, b2, out);
}

// Round 3
// 226.792 us; speedup vs baseline: 1.0425x; 1.0377x over previous
//
#include <hip/hip_runtime.h>

#define N_NODES 50000
#define N_EDGES 800000
#define IN_FEATS 256
#define HIDDEN 128
#define OUT_FEATS 64

// ---- LDS-histogram decomposition (packed u16 counters) ----
// R12: NB 8192 (32 KB LDS), NRANGE 7; gemm1 fused into hist launch.
// R14: gemm1 restructured — one block does BOTH 64-col halves (x read 1x,
// not 2x), 32 KB unpadded XOR-swizzled Bs (T2), x row-frags held in VGPRs.
// Grid 448 hist + 782 gemm. Targets the measured 45.5 us top dispatch
// (Occ 31%, VALU 14%, MFMA 2.4% => latency-bound).
#define NB 8192              // bins per range (2 bins/u32 word -> 16 KB LDS)
#define NRANGE 7             // ceil(50000/8192)
#define NBT (NRANGE * NB)    // 57344 padded bins per copy (u16 each)
#define NCHUNK 64            // edge chunks (= privatized copies)
#define EPC 12500            // edges per chunk; per-bin count <= 12500 < 2^16
#define HBLK (NRANGE * NCHUNK)           // 448 hist blocks
#define ROWBLK ((N_NODES + 63) / 64)     // 782

typedef _Float16 f16;
typedef _Float16 f16x2 __attribute__((ext_vector_type(2)));
typedef _Float16 f16x8 __attribute__((ext_vector_type(8)));
typedef float f32x4 __attribute__((ext_vector_type(4)));

// ------------------------------------------- fused hist + gemm1 kernel
// Blocks [0,448): LDS histogram of src/dst (zero global atomics) + W2T
// transpose fold on blocks 0-31. Blocks [448, 1230): gemm1 m1 = f16(X)@W1
// (UNSCALED — norm_src applied per-edge in gather1 by linearity).
__global__ __launch_bounds__(256) void hist_gemm_kernel(
    const int* __restrict__ src, const int* __restrict__ dst,
    unsigned* __restrict__ hist_src, unsigned* __restrict__ hist_dst,
    const float* __restrict__ W1, const float* __restrict__ W2,
    f16* __restrict__ W2T, const float* __restrict__ x,
    f16* __restrict__ m1) {
  // union: hist counters (32 KB) / gemm B-tile 64x256 f16 swizzled (32 KB)
  __shared__ __align__(16) unsigned smem[8192];  // 32768 B exactly
  if (blockIdx.x < HBLK) {
    unsigned* ls = smem;            // [NB/2] packed u16 src-degree bins
    unsigned* ld2 = smem + NB / 2;  // [NB/2] packed u16 dst-degree bins
    const int r = blockIdx.x % NRANGE;
    const int c = blockIdx.x / NRANGE;
    const int lo = r * NB;
    for (int i = threadIdx.x; i < NB / 2; i += 256) {
      ls[i] = 0;
      ld2[i] = 0;
    }
    __syncthreads();
    const int4* s4 = (const int4*)(src + c * EPC);
    const int4* d4 = (const int4*)(dst + c * EPC);
    for (int i = threadIdx.x; i < EPC / 4; i += 256) {
      int4 s = s4[i];
      int4 d = d4[i];
      unsigned b;
      b = (unsigned)(s.x - lo); if (b < NB) atomicAdd(&ls[b >> 1], 1u << ((b & 1) << 4));
      b = (unsigned)(s.y - lo); if (b < NB) atomicAdd(&ls[b >> 1], 1u << ((b & 1) << 4));
      b = (unsigned)(s.z - lo); if (b < NB) atomicAdd(&ls[b >> 1], 1u << ((b & 1) << 4));
      b = (unsigned)(s.w - lo); if (b < NB) atomicAdd(&ls[b >> 1], 1u << ((b & 1) << 4));
      b = (unsigned)(d.x - lo); if (b < NB) atomicAdd(&ld2[b >> 1], 1u << ((b & 1) << 4));
      b = (unsigned)(d.y - lo); if (b < NB) atomicAdd(&ld2[b >> 1], 1u << ((b & 1) << 4));
      b = (unsigned)(d.z - lo); if (b < NB) atomicAdd(&ld2[b >> 1], 1u << ((b & 1) << 4));
      b = (unsigned)(d.w - lo); if (b < NB) atomicAdd(&ld2[b >> 1], 1u << ((b & 1) << 4));
    }
    __syncthreads();
    unsigned* hs = hist_src + ((long)c * NBT + lo) / 2;
    unsigned* hd = hist_dst + ((long)c * NBT + lo) / 2;
    for (int i = threadIdx.x; i < NB / 2; i += 256) {
      hs[i] = ls[i];
      hd[i] = ld2[i];
    }
    // folded W2 transpose: 8192 elems on blocks 0-31
    if (blockIdx.x < 32) {
      int j = blockIdx.x * 256 + threadIdx.x;
      int n = j >> 7, k = j & 127;
      W2T[j] = (f16)W2[k * 64 + n];
    }
  } else {
    // ------- gemm1: 64-row x 128-col tile, two 64-col halves, one 32 KB
    // swizzled Bs. Swizzle (both sides, same involution): byte ^= (n&7)<<4
    // where n = logical row (output col) of Bs[64][256] f16.
    char* BsBytes = (char*)smem;
    const int rb = blockIdx.x - HBLK;
    const int wave = threadIdx.x >> 6;
    const int lane = threadIdx.x & 63;
    const int m = lane & 15;
    const int q = lane >> 4;
    const int row0 = rb * 64 + wave * 16;
    const int ra = min(row0 + m, N_NODES - 1);

    // load + convert this lane's x row fragments ONCE (8 x f16x8 = 32 VGPR)
    f16x8 a[8];
#pragma unroll
    for (int ki = 0; ki < 8; ++ki) {
      const float* p = x + (long)ra * IN_FEATS + ki * 32 + q * 8;
      float4 u0 = *(const float4*)p;
      float4 u1 = *(const float4*)(p + 4);
      a[ki][0] = (f16)u0.x; a[ki][1] = (f16)u0.y;
      a[ki][2] = (f16)u0.z; a[ki][3] = (f16)u0.w;
      a[ki][4] = (f16)u1.x; a[ki][5] = (f16)u1.y;
      a[ki][6] = (f16)u1.z; a[ki][7] = (f16)u1.w;
    }

    for (int h = 0; h < 2; ++h) {
      const int col0 = h * 64;
      // stage Bs[n][k] = W1[k][col0+n]; coalesced global (n per lane),
      // f16x2-packed swizzled LDS writes (8-way spread, cheap).
      for (int idx = threadIdx.x; idx < 64 * 128; idx += 256) {
        int k2 = idx >> 6;   // k = 2*k2
        int n = idx & 63;
        float a0 = W1[(2 * k2) * HIDDEN + col0 + n];
        float a1 = W1[(2 * k2 + 1) * HIDDEN + col0 + n];
        f16x2 pk;
        pk[0] = (f16)a0;
        pk[1] = (f16)a1;
        unsigned bo = (unsigned)(n * 512 + 4 * k2);
        bo ^= (unsigned)((n & 7) << 4);
        *(f16x2*)(BsBytes + bo) = pk;
      }
      __syncthreads();

      f32x4 acc[4];
#pragma unroll
      for (int t = 0; t < 4; ++t) acc[t] = (f32x4){0.f, 0.f, 0.f, 0.f};

#pragma unroll
      for (int ki = 0; ki < 8; ++ki) {
        const int kb2 = (ki * 32 + q * 8) * 2;  // byte offset in row
#pragma unroll
        for (int t = 0; t < 4; ++t) {
          int nrow = t * 16 + m;
          unsigned bo = (unsigned)(nrow * 512 + kb2);
          bo ^= (unsigned)((nrow & 7) << 4);
          f16x8 bfr = *(const f16x8*)(BsBytes + bo);
          acc[t] = __builtin_amdgcn_mfma_f32_16x16x32_f16(a[ki], bfr, acc[t], 0, 0, 0);
        }
      }
      __syncthreads();  // all reads of Bs done before next half's restage

#pragma unroll
      for (int rr = 0; rr < 4; ++rr) {
        int row = row0 + q * 4 + rr;
        if (row < N_NODES) {
#pragma unroll
          for (int t = 0; t < 4; ++t)
            m1[(long)row * HIDDEN + col0 + t * 16 + m] = (f16)acc[t][rr];
        }
      }
    }
  }
}

// sum copies -> norms; hist_dst -> exclusive prefix over copies (u16; max
// in-degree ~50 << 2^16); emits per-block degree sums (folded scan1).
__global__ __launch_bounds__(256) void reduce_kernel(
    const unsigned* __restrict__ hist_src, unsigned* __restrict__ hist_dst,
    int* __restrict__ deg_in, float* __restrict__ norm_src,
    float* __restrict__ norm_dst, int* __restrict__ partial) {
  const unsigned short* hs = (const unsigned short*)hist_src;
  unsigned short* hd = (unsigned short*)hist_dst;
  int n = blockIdx.x * 256 + threadIdx.x;
  int run = 0;
  if (n < N_NODES) {
    int so = 0;
#pragma unroll 8
    for (int c = 0; c < NCHUNK; ++c) so += hs[(long)c * NBT + n];
    norm_src[n] = rsqrtf((float)max(so, 1));
#pragma unroll 8
    for (int c = 0; c < NCHUNK; ++c) {
      int t = hd[(long)c * NBT + n];
      hd[(long)c * NBT + n] = (unsigned short)run;
      run += t;
    }
    deg_in[n] = run;
    norm_dst[n] = rsqrtf((float)max(run, 1));
  }
  __shared__ int sd[256];
  sd[threadIdx.x] = run;
  __syncthreads();
  for (int s = 128; s > 0; s >>= 1) {
    if (threadIdx.x < s) sd[threadIdx.x] += sd[threadIdx.x + s];
    __syncthreads();
  }
  if (threadIdx.x == 0) partial[blockIdx.x] = sd[0];
}

// ------------------------------------------------- scan (scan2 folded in)
__global__ __launch_bounds__(256) void scan3(const int* __restrict__ deg,
                                             const int* __restrict__ partial,
                                             int* __restrict__ rowptr) {
  __shared__ int sd[256];
  __shared__ int sp[256];
  const int w = blockIdx.x;
  int pv = (threadIdx.x < 196) ? partial[threadIdx.x] : 0;
  sp[threadIdx.x] = pv;
  __syncthreads();
  for (int off = 1; off < 256; off <<= 1) {
    int t = sp[threadIdx.x] +
            ((threadIdx.x >= off) ? sp[threadIdx.x - off] : 0);
    __syncthreads();
    sp[threadIdx.x] = t;
    __syncthreads();
  }
  const int base = (w == 0) ? 0 : sp[w - 1];
  int i = w * 256 + threadIdx.x;
  int v = (i < N_NODES) ? deg[i] : 0;
  sd[threadIdx.x] = v;
  __syncthreads();
  for (int off = 1; off < 256; off <<= 1) {
    int t = sd[threadIdx.x] +
            ((threadIdx.x >= off) ? sd[threadIdx.x - off] : 0);
    __syncthreads();
    sd[threadIdx.x] = t;
    __syncthreads();
  }
  if (i < N_NODES) rowptr[i] = base + sd[threadIdx.x] - v;
  if (w == 0 && threadIdx.x == 0) rowptr[N_NODES] = N_EDGES;
}

// ------------------------------------------------------------- CSR fill
__global__ __launch_bounds__(256) void fill_csr(
    const int* __restrict__ src, const int* __restrict__ dst,
    const int* __restrict__ rowptr, const unsigned* __restrict__ pref32,
    int* __restrict__ col) {
  __shared__ int cur[NB];  // 32 KB
  const unsigned short* pref = (const unsigned short*)pref32;
  const int r = blockIdx.x % NRANGE;
  const int c = blockIdx.x / NRANGE;
  const int lo = r * NB;
  for (int i = threadIdx.x; i < NB; i += 256) {
    int n = lo + i;
    cur[i] = (n < N_NODES) ? rowptr[n] + pref[(long)c * NBT + n] : 0;
  }
  __syncthreads();
  const int4* s4 = (const int4*)(src + c * EPC);
  const int4* d4 = (const int4*)(dst + c * EPC);
  for (int i = threadIdx.x; i < EPC / 4; i += 256) {
    int4 s = s4[i];
    int4 d = d4[i];
    unsigned b;
    b = (unsigned)(d.x - lo);
    if (b < NB) col[atomicAdd(&cur[b], 1)] = s.x;
    b = (unsigned)(d.y - lo);
    if (b < NB) col[atomicAdd(&cur[b], 1)] = s.y;
    b = (unsigned)(d.z - lo);
    if (b < NB) col[atomicAdd(&cur[b], 1)] = s.z;
    b = (unsigned)(d.w - lo);
    if (b < NB) col[atomicAdd(&cur[b], 1)] = s.w;
  }
}

// ------------------------------------------------------------- MFMA GEMM
// (layer 2 only; layer 1 is fused into hist_gemm_kernel)
template <int K, int NC, int TN, bool FP32IN>
__global__ __launch_bounds__(256) void gemm_mfma(
    const void* __restrict__ Xv, const f16* __restrict__ WT,
    const float* __restrict__ ns, f16* __restrict__ Mout) {
  constexpr int KI = K / 32;
  constexpr int COLBLK = NC / (TN * 16);
  constexpr int KP = K + 8;
  __shared__ f16 Bs[TN * 16 * KP];

  const int cb = blockIdx.x % COLBLK;
  const int rb = blockIdx.x / COLBLK;
  const int col0 = cb * TN * 16;
  const int wave = threadIdx.x >> 6;
  const int lane = threadIdx.x & 63;
  const int m = lane & 15;
  const int q = lane >> 4;
  const int row0 = rb * 64 + wave * 16;

  for (int idx = threadIdx.x; idx < TN * 16 * (K / 8); idx += 256) {
    int n = idx / (K / 8);
    int kk = idx % (K / 8);
    *(f16x8*)(Bs + n * KP + kk * 8) =
        *(const f16x8*)(WT + (long)(col0 + n) * K + kk * 8);
  }
  __syncthreads();

  const int ra = min(row0 + m, N_NODES - 1);
  const float s = FP32IN ? ns[ra] : 0.f;

  f32x4 acc[TN];
#pragma unroll
  for (int t = 0; t < TN; ++t) acc[t] = (f32x4){0.f, 0.f, 0.f, 0.f};

#pragma unroll
  for (int ki = 0; ki < KI; ++ki) {
    const int kb = ki * 32 + q * 8;
    f16x8 a;
    if (FP32IN) {
      const float* X = (const float*)Xv;
      const float* p = X + (long)ra * K + kb;
      float4 u0 = *(const float4*)p;
      float4 u1 = *(const float4*)(p + 4);
      a[0] = (f16)(u0.x * s); a[1] = (f16)(u0.y * s);
      a[2] = (f16)(u0.z * s); a[3] = (f16)(u0.w * s);
      a[4] = (f16)(u1.x * s); a[5] = (f16)(u1.y * s);
      a[6] = (f16)(u1.z * s); a[7] = (f16)(u1.w * s);
    } else {
      const f16* X = (const f16*)Xv;
      a = *(const f16x8*)(X + (long)ra * K + kb);
    }
#pragma unroll
    for (int t = 0; t < TN; ++t) {
      f16x8 b = *(const f16x8*)(Bs + (t * 16 + m) * KP + kb);
      acc[t] = __builtin_amdgcn_mfma_f32_16x16x32_f16(a, b, acc[t], 0, 0, 0);
    }
  }

#pragma unroll
  for (int r = 0; r < 4; ++r) {
    int row = row0 + q * 4 + r;
    if (row < N_NODES) {
#pragma unroll
      for (int t = 0; t < TN; ++t)
        Mout[(long)row * NC + col0 + t * 16 + m] = (f16)acc[t][r];
    }
  }
}

// ------------------------------------------------------------- gather-agg
// R6/R10 measured-best form; R12: per-edge ns[col] scaling (m1 unscaled).
__global__ __launch_bounds__(256) void gather1_kernel(
    const f16* __restrict__ M, const int* __restrict__ rowptr,
    const int* __restrict__ col, const float* __restrict__ nd,
    const float* __restrict__ ns, const float* __restrict__ b,
    f16* __restrict__ out) {
  constexpr int LPR = 16;       // 128 f16 = 256 B row / 16 B per lane
  constexpr int EPW = 64 / LPR; // 4 edges in parallel
  const int wave = threadIdx.x >> 6;
  const int lane = threadIdx.x & 63;
  const int eg = lane / LPR;
  const int t = lane % LPR;
  const int n = blockIdx.x * 4 + wave;
  if (n >= N_NODES) return;
  const int beg = rowptr[n];
  const int end = rowptr[n + 1];

  float acc[8];
#pragma unroll
  for (int j = 0; j < 8; ++j) acc[j] = 0.f;

  int i = beg + eg;
  for (; i + EPW < end; i += 2 * EPW) {
    int s0 = col[i];
    int s1 = col[i + EPW];
    float n0 = ns[s0];
    float n1 = ns[s1];
    f16x8 v0 = *(const f16x8*)(M + (long)s0 * HIDDEN + t * 8);
    f16x8 v1 = *(const f16x8*)(M + (long)s1 * HIDDEN + t * 8);
#pragma unroll
    for (int j = 0; j < 8; ++j)
      acc[j] += n0 * (float)v0[j] + n1 * (float)v1[j];
  }
  if (i < end) {
    int s0 = col[i];
    float n0 = ns[s0];
    f16x8 v0 = *(const f16x8*)(M + (long)s0 * HIDDEN + t * 8);
#pragma unroll
    for (int j = 0; j < 8; ++j) acc[j] += n0 * (float)v0[j];
  }

#pragma unroll
  for (int m2 = LPR; m2 < 64; m2 <<= 1)
#pragma unroll
    for (int j = 0; j < 8; ++j) acc[j] += __shfl_xor(acc[j], m2, 64);

  if (eg == 0) {
    float s = nd[n];
    float sn = ns[n];
    float4 bb0 = *(const float4*)(b + t * 8);
    float4 bb1 = *(const float4*)(b + t * 8 + 4);
    f16x8 o;
    o[0] = (f16)(fmaxf(acc[0] * s + bb0.x, 0.f) * sn);
    o[1] = (f16)(fmaxf(acc[1] * s + bb0.y, 0.f) * sn);
    o[2] = (f16)(fmaxf(acc[2] * s + bb0.z, 0.f) * sn);
    o[3] = (f16)(fmaxf(acc[3] * s + bb0.w, 0.f) * sn);
    o[4] = (f16)(fmaxf(acc[4] * s + bb1.x, 0.f) * sn);
    o[5] = (f16)(fmaxf(acc[5] * s + bb1.y, 0.f) * sn);
    o[6] = (f16)(fmaxf(acc[6] * s + bb1.z, 0.f) * sn);
    o[7] = (f16)(fmaxf(acc[7] * s + bb1.w, 0.f) * sn);
    *(f16x8*)(out + (long)n * HIDDEN + t * 8) = o;
  }
}

__global__ __launch_bounds__(256) void gather2_kernel(
    const f16* __restrict__ M, const int* __restrict__ rowptr,
    const int* __restrict__ col, const float* __restrict__ nd,
    const float* __restrict__ b, float* __restrict__ out) {
  constexpr int LPR = 8;        // 64 f16 = 128 B row / 16 B per lane
  constexpr int EPW = 64 / LPR; // 8 edges in parallel
  const int wave = threadIdx.x >> 6;
  const int lane = threadIdx.x & 63;
  const int eg = lane / LPR;
  const int t = lane % LPR;
  const int n = blockIdx.x * 4 + wave;
  if (n >= N_NODES) return;
  const int beg = rowptr[n];
  const int end = rowptr[n + 1];

  float acc[8];
#pragma unroll
  for (int j = 0; j < 8; ++j) acc[j] = 0.f;

  int i = beg + eg;
  for (; i + EPW < end; i += 2 * EPW) {
    int s0 = col[i];
    int s1 = col[i + EPW];
    f16x8 v0 = *(const f16x8*)(M + (long)s0 * OUT_FEATS + t * 8);
    f16x8 v1 = *(const f16x8*)(M + (long)s1 * OUT_FEATS + t * 8);
#pragma unroll
    for (int j = 0; j < 8; ++j) acc[j] += (float)v0[j] + (float)v1[j];
  }
  if (i < end) {
    int s0 = col[i];
    f16x8 v0 = *(const f16x8*)(M + (long)s0 * OUT_FEATS + t * 8);
#pragma unroll
    for (int j = 0; j < 8; ++j) acc[j] += (float)v0[j];
  }

#pragma unroll
  for (int m2 = LPR; m2 < 64; m2 <<= 1)
#pragma unroll
    for (int j = 0; j < 8; ++j) acc[j] += __shfl_xor(acc[j], m2, 64);

  if (eg == 0) {
    float s = nd[n];
    float4 bb0 = *(const float4*)(b + t * 8);
    float4 bb1 = *(const float4*)(b + t * 8 + 4);
    float4 o0, o1;
    o0.x = acc[0] * s + bb0.x;
    o0.y = acc[1] * s + bb0.y;
    o0.z = acc[2] * s + bb0.z;
    o0.w = acc[3] * s + bb0.w;
    o1.x = acc[4] * s + bb1.x;
    o1.y = acc[5] * s + bb1.y;
    o1.z = acc[6] * s + bb1.z;
    o1.w = acc[7] * s + bb1.w;
    *(float4*)(out + (long)n * OUT_FEATS + t * 8) = o0;
    *(float4*)(out + (long)n * OUT_FEATS + t * 8 + 4) = o1;
  }
}

extern "C" void kernel_launch(void* const* d_in, const int* in_sizes, int n_in,
                              void* d_out, int out_size, void* d_ws,
                              size_t ws_size, hipStream_t stream) {
  const float* x = (const float*)d_in[0];
  const int* src = (const int*)d_in[1];
  const int* dst = (const int*)d_in[2];
  const float* W1 = (const float*)d_in[3];
  const float* b1 = (const float*)d_in[4];
  const float* W2 = (const float*)d_in[5];
  const float* b2 = (const float*)d_in[6];
  float* out = (float*)d_out;

  // ---- workspace layout
  int* wi = (int*)d_ws;
  int* partial = wi;            // [256]
  int* rowptr = wi + 256;       // [50001] (pad to 50004)
  int* deg_in = wi + 50260;     // [50000]
  int* col = wi + 100260;       // [800000] -> ends at int 900260
  float* wf = (float*)d_ws + 900260;
  float* norm_src = wf;         // [50000]
  float* norm_dst = wf + 50000; // [50000]
  f16* fh = (f16*)(wf + 100000);
  f16* W2T = fh;                          // [64*128]
  f16* m1 = fh + 64 * 128;                // [50048*128]
  f16* h1p = m1 + (long)50048 * 128;      // [50048*128]
  f16* m2 = h1p + (long)50048 * 128;      // [50048*64]

  // hist overlay on h1p/m2 region (19.2 MB >= 14.7 MB): m1 must stay live
  // (gemm1 writes it during the hist launch); h1p/m2 are dead until
  // gather1/gemm2, which run after fill_csr (stream-ordered).
  unsigned* hist_src = (unsigned*)h1p;                      // u16[NCHUNK*NBT]
  unsigned* hist_dst = hist_src + (long)NCHUNK * NBT / 2;   // u16[NCHUNK*NBT]

  const int nb_nodes = (N_NODES + 255) / 256;  // 196

  // ---- fused: degrees histogram + W2 transpose + gemm1 (independent work)
  hist_gemm_kernel<<<HBLK + ROWBLK, 256, 0, stream>>>(
      src, dst, hist_src, hist_dst, W1, W2, W2T, x, m1);
  reduce_kernel<<<nb_nodes, 256, 0, stream>>>(hist_src, hist_dst, deg_in,
                                              norm_src, norm_dst, partial);
  scan3<<<nb_nodes, 256, 0, stream>>>(deg_in, partial, rowptr);
  fill_csr<<<HBLK, 256, 0, stream>>>(src, dst, rowptr, hist_dst, col);

  // ---- layer 1 aggregation (applies ns[src] per edge)
  gather1_kernel<<<(N_NODES + 3) / 4, 256, 0, stream>>>(m1, rowptr, col,
                                                        norm_dst, norm_src, b1,
                                                        h1p);

  // ---- layer 2
  gemm_mfma<HIDDEN, OUT_FEATS, 4, false>
      <<<ROWBLK, 256, 0, stream>>>(h1p, W2T, norm_src, m2);
  gather2_kernel<<<(N_NODES + 3) / 4, 256, 0, stream>>>(m2, rowptr, col,
                                                        norm_dst, b2, out);
}